// Round 3
// baseline (767.011 us; speedup 1.0000x reference)
//
#include <hip/hip_runtime.h>

// RGCN 2-layer, N=100000, E=3200000, R=8, H=C=16.
// Pipeline: fine histogram (dst>>6) -> scan -> 2-level radix partition by dst
// (coarse 49 buckets, fine 1563 buckets of 64 nodes; L2-local writes) ->
// per-fine-bucket layer blocks: stream edges, ds_add_f32 per-(node,rel) sums
// + LDS counts (no global CSR/count tables), then 4 rel-block MFMAs + root
// MFMA + fused relu / log_softmax. h stored bf16 for layer-2 gathers.

constexpr int NN = 100000;
constexpr int NE = 3200000;
constexpr int NFINE = 1563;    // ceil(NN/64)
constexpr int NCOARSE = 49;    // ceil(NN/2048)

typedef short bf16x8 __attribute__((ext_vector_type(8)));
typedef float f32x4 __attribute__((ext_vector_type(4)));

__device__ __forceinline__ short f2bf(float f) {
  union { float f; unsigned u; } v; v.f = f;
  unsigned r = v.u + 0x7FFFu + ((v.u >> 16) & 1u);  // RNE
  return (short)(r >> 16);
}
__device__ __forceinline__ float bf2f(unsigned short u) {
  union { unsigned u; float f; } v; v.u = ((unsigned)u) << 16; return v.f;
}

// K1: fine-bucket histogram (bucket = dst>>6), LDS-aggregated.
__global__ void __launch_bounds__(256) hist_kernel(
    const int* __restrict__ dst, unsigned* __restrict__ fcnt) {
  __shared__ unsigned h[NFINE];
  for (int i = threadIdx.x; i < NFINE; i += 256) h[i] = 0u;
  __syncthreads();
  const int base = blockIdx.x * 8192;
#pragma unroll
  for (int i = 0; i < 32; ++i) {
    int e = base + i * 256 + threadIdx.x;
    if (e < NE) atomicAdd(&h[(unsigned)dst[e] >> 6], 1u);
  }
  __syncthreads();
  for (int i = threadIdx.x; i < NFINE; i += 256)
    if (h[i]) atomicAdd(&fcnt[i], h[i]);
}

// K2: single-block exclusive scan of fcnt -> foff[0..NFINE], fine cursors,
// coarse boundaries (cbnd[c] = foff[min(32c,NFINE)]) and coarse cursors.
__global__ void __launch_bounds__(256) scan_kernel(
    const unsigned* __restrict__ fcnt, unsigned* __restrict__ foff,
    unsigned* __restrict__ fcur, unsigned* __restrict__ cbnd,
    unsigned* __restrict__ ccur) {
  __shared__ unsigned sh[256];
  unsigned v[7], s = 0;
#pragma unroll
  for (int j = 0; j < 7; ++j) {
    int idx = threadIdx.x * 7 + j;
    v[j] = (idx < NFINE) ? fcnt[idx] : 0u;
    s += v[j];
  }
  sh[threadIdx.x] = s;
  __syncthreads();
  for (int d = 1; d < 256; d <<= 1) {
    unsigned t = (threadIdx.x >= d) ? sh[threadIdx.x - d] : 0u;
    __syncthreads();
    sh[threadIdx.x] += t;
    __syncthreads();
  }
  unsigned run = sh[threadIdx.x] - s;
#pragma unroll
  for (int j = 0; j < 7; ++j) {
    int idx = threadIdx.x * 7 + j;
    if (idx <= NFINE) foff[idx] = run;
    if (idx < NFINE) fcur[idx] = run;
    run += v[j];
  }
  __syncthreads();
  if (threadIdx.x <= NCOARSE) {
    int f = threadIdx.x * 32; if (f > NFINE) f = NFINE;
    unsigned b = foff[f];
    cbnd[threadIdx.x] = b;
    if (threadIdx.x < NCOARSE) ccur[threadIdx.x] = b;
  }
}

// K3: coarse partition (dst>>11). Entry = src | rel<<17 | (dst&2047)<<20.
__global__ void __launch_bounds__(256) part1_kernel(
    const int* __restrict__ src, const int* __restrict__ dst,
    const int* __restrict__ typ, unsigned* __restrict__ ccur,
    unsigned* __restrict__ buf1) {
  __shared__ unsigned hist[NCOARSE];
  __shared__ unsigned gb[NCOARSE];
  if (threadIdx.x < NCOARSE) hist[threadIdx.x] = 0u;
  __syncthreads();
  const int base = blockIdx.x * 4096;
  unsigned ent[16], cb[16], rk[16];
#pragma unroll
  for (int i = 0; i < 16; ++i) {
    int e = base + i * 256 + threadIdx.x;
    if (e < NE) {
      unsigned d = (unsigned)dst[e];
      ent[i] = (unsigned)src[e] | ((unsigned)typ[e] << 17) | ((d & 2047u) << 20);
      cb[i] = d >> 11;
      rk[i] = atomicAdd(&hist[cb[i]], 1u);
    } else cb[i] = 0xFFFFFFFFu;
  }
  __syncthreads();
  if (threadIdx.x < NCOARSE && hist[threadIdx.x])
    gb[threadIdx.x] = atomicAdd(&ccur[threadIdx.x], hist[threadIdx.x]);
  __syncthreads();
#pragma unroll
  for (int i = 0; i < 16; ++i)
    if (cb[i] != 0xFFFFFFFFu) buf1[gb[cb[i]] + rk[i]] = ent[i];
}

// K4: fine partition within coarse segments. Final entry = low 26 bits
// (src | rel<<17 | dstl<<20); fine id recovered from position + entry bits.
__global__ void __launch_bounds__(256) part2_kernel(
    const unsigned* __restrict__ buf1, const unsigned* __restrict__ cbnd,
    unsigned* __restrict__ fcur, unsigned* __restrict__ buf2) {
  __shared__ unsigned hist[NFINE];
  __shared__ unsigned gb[NFINE];
  __shared__ unsigned cb_s[NCOARSE + 1];
  for (int i = threadIdx.x; i < NFINE; i += 256) hist[i] = 0u;
  if (threadIdx.x <= NCOARSE) cb_s[threadIdx.x] = cbnd[threadIdx.x];
  __syncthreads();
  const unsigned base = blockIdx.x * 4096u;
  int cc = 0;
  while (cc < NCOARSE - 1 && base >= cb_s[cc + 1]) ++cc;
  unsigned ent[16], fn[16], rk[16];
#pragma unroll
  for (int i = 0; i < 16; ++i) {
    unsigned p = base + i * 256u + threadIdx.x;
    if (p < (unsigned)NE) {
      unsigned e = buf1[p];
      while (p >= cb_s[cc + 1]) ++cc;
      fn[i] = (unsigned)cc * 32u + ((e >> 26) & 31u);
      ent[i] = e & 0x03FFFFFFu;
      rk[i] = atomicAdd(&hist[fn[i]], 1u);
    } else fn[i] = 0xFFFFFFFFu;
  }
  __syncthreads();
  for (int i = threadIdx.x; i < NFINE; i += 256)
    if (hist[i]) gb[i] = atomicAdd(&fcur[i], hist[i]);
  __syncthreads();
#pragma unroll
  for (int i = 0; i < 16; ++i)
    if (fn[i] != 0xFFFFFFFFu) buf2[gb[fn[i]] + rk[i]] = ent[i];
}

// K5/K6: per-fine-bucket layer. Block = 64 nodes. Stream edge segment:
// 16-lane groups gather x[src][c], ds_add_f32 into S[node][rel][c] + LDS
// counts. Then 4 waves x 16-node MFMA tiles (4 rel-block MFMAs + root) with
// invc folded into the A-fragment load; fused relu / log_softmax epilogue.
template <int MODE>
__global__ void __launch_bounds__(256) layer_kernel(
    const float* __restrict__ Xf, const unsigned short* __restrict__ Xh,
    const float* __restrict__ W, const float* __restrict__ ROOT,
    const float* __restrict__ BIAS, const unsigned* __restrict__ foff,
    const unsigned* __restrict__ buf2, unsigned short* __restrict__ Hout,
    float* __restrict__ Fout) {
  __shared__ float S[64 * 132];   // node stride 132 (16B-aligned loads)
  __shared__ unsigned CNT[64 * 8];
  const int tid = threadIdx.x;
  for (int i = tid; i < 64 * 132; i += 256) S[i] = 0.f;
  CNT[tid] = 0u; CNT[tid + 256] = 0u;
  __syncthreads();

  const unsigned p0 = foff[blockIdx.x], p1 = foff[blockIdx.x + 1];
  const int gi = tid >> 4;   // 16 groups of 16 lanes
  const int c16 = tid & 15;

  auto LDX = [&](unsigned e) -> float {
    unsigned sr = (e <= 0x03FFFFFFu) ? (e & 0x1FFFFu) : 0u;
    if (MODE) return bf2f(Xh[(size_t)sr * 16 + c16]);
    return Xf[(size_t)sr * 16 + c16];
  };
  auto PROC = [&](unsigned e, float xv) {
    if (e <= 0x03FFFFFFu) {
      unsigned rel = (e >> 17) & 7u, dl = (e >> 20) & 63u;
      atomicAdd(&S[dl * 132 + rel * 16 + c16], xv);
      if (c16 == 0) atomicAdd(&CNT[dl * 8 + rel], 1u);
    }
  };

  for (unsigned p = p0 + gi; p < p1; p += 64) {
    unsigned e0 = buf2[p];
    unsigned e1 = (p + 16 < p1) ? buf2[p + 16] : 0xFFFFFFFFu;
    unsigned e2 = (p + 32 < p1) ? buf2[p + 32] : 0xFFFFFFFFu;
    unsigned e3 = (p + 48 < p1) ? buf2[p + 48] : 0xFFFFFFFFu;
    float x0 = LDX(e0), x1 = LDX(e1), x2 = LDX(e2), x3 = LDX(e3);
    PROC(e0, x0); PROC(e1, x1); PROC(e2, x2); PROC(e3, x3);
  }
  __syncthreads();

  // MFMA phase: wave w owns nodes w*16..w*16+15 of this bucket.
  const int lane = tid & 63;
  const int fc = lane & 15;
  const int g = lane >> 4;
  const int w = tid >> 6;
  const int n0 = blockIdx.x * 64 + w * 16;

  bf16x8 b0, b1, b2, b3, brt;
#pragma unroll
  for (int j = 0; j < 8; ++j) {
    int kq = g * 8 + j; int rb = kq >> 4; int kk = kq & 15;
    b0[j] = f2bf(W[(rb + 0) * 256 + kk * 16 + fc]);
    b1[j] = f2bf(W[(rb + 2) * 256 + kk * 16 + fc]);
    b2[j] = f2bf(W[(rb + 4) * 256 + kk * 16 + fc]);
    b3[j] = f2bf(W[(rb + 6) * 256 + kk * 16 + fc]);
    brt[j] = (kq < 16) ? f2bf(ROOT[kq * 16 + fc]) : (short)0;
  }

  const int kk0 = (g & 1) * 8;
  const int rsel = g >> 1;
  const int dl16 = w * 16 + fc;
  bf16x8 a0, a1, a2, a3;
#define LDA(AM, M)                                                        \
  {                                                                       \
    unsigned ct = CNT[dl16 * 8 + 2 * (M) + rsel];                         \
    float iv = 1.f / (float)(ct ? ct : 1u);                               \
    const float* sp2 = S + dl16 * 132 + (2 * (M) + rsel) * 16 + kk0;      \
    float4 u = *reinterpret_cast<const float4*>(sp2);                     \
    float4 v2 = *reinterpret_cast<const float4*>(sp2 + 4);                \
    AM[0] = f2bf(u.x * iv); AM[1] = f2bf(u.y * iv);                       \
    AM[2] = f2bf(u.z * iv); AM[3] = f2bf(u.w * iv);                       \
    AM[4] = f2bf(v2.x * iv); AM[5] = f2bf(v2.y * iv);                     \
    AM[6] = f2bf(v2.z * iv); AM[7] = f2bf(v2.w * iv);                     \
  }
  LDA(a0, 0) LDA(a1, 1) LDA(a2, 2) LDA(a3, 3)
#undef LDA

  bf16x8 ar = {0, 0, 0, 0, 0, 0, 0, 0};
  if (g < 2) {
    int node = n0 + fc;
    if (node < NN) {
      if (MODE == 0) {
        const float* xp = Xf + (size_t)node * 16 + g * 8;
        float4 pp = *reinterpret_cast<const float4*>(xp);
        float4 qq = *reinterpret_cast<const float4*>(xp + 4);
        ar[0] = f2bf(pp.x); ar[1] = f2bf(pp.y); ar[2] = f2bf(pp.z);
        ar[3] = f2bf(pp.w); ar[4] = f2bf(qq.x); ar[5] = f2bf(qq.y);
        ar[6] = f2bf(qq.z); ar[7] = f2bf(qq.w);
      } else {
        ar = *reinterpret_cast<const bf16x8*>(Xh + (size_t)node * 16 + g * 8);
      }
    }
  }

  const float bc = BIAS[fc];
  f32x4 acc = {bc, bc, bc, bc};
  acc = __builtin_amdgcn_mfma_f32_16x16x32_bf16(a0, b0, acc, 0, 0, 0);
  acc = __builtin_amdgcn_mfma_f32_16x16x32_bf16(a1, b1, acc, 0, 0, 0);
  acc = __builtin_amdgcn_mfma_f32_16x16x32_bf16(a2, b2, acc, 0, 0, 0);
  acc = __builtin_amdgcn_mfma_f32_16x16x32_bf16(a3, b3, acc, 0, 0, 0);
  acc = __builtin_amdgcn_mfma_f32_16x16x32_bf16(ar, brt, acc, 0, 0, 0);

  if (MODE == 0) {
#pragma unroll
    for (int r2 = 0; r2 < 4; ++r2) {
      int node = n0 + g * 4 + r2;
      if (node < NN)
        Hout[(size_t)node * 16 + fc] = (unsigned short)f2bf(fmaxf(acc[r2], 0.f));
    }
  } else {
#pragma unroll
    for (int r2 = 0; r2 < 4; ++r2) {
      int node = n0 + g * 4 + r2;
      float zv = acc[r2];
      float mx = zv;
      mx = fmaxf(mx, __shfl_xor(mx, 1));
      mx = fmaxf(mx, __shfl_xor(mx, 2));
      mx = fmaxf(mx, __shfl_xor(mx, 4));
      mx = fmaxf(mx, __shfl_xor(mx, 8));
      float sm = expf(zv - mx);
      sm += __shfl_xor(sm, 1);
      sm += __shfl_xor(sm, 2);
      sm += __shfl_xor(sm, 4);
      sm += __shfl_xor(sm, 8);
      if (node < NN)
        Fout[(size_t)node * 16 + fc] = zv - mx - logf(sm);
    }
  }
}

extern "C" void kernel_launch(void* const* d_in, const int* in_sizes, int n_in,
                              void* d_out, int out_size, void* d_ws, size_t ws_size,
                              hipStream_t stream) {
  const float* embed = (const float*)d_in[0];
  const float* W1    = (const float*)d_in[1];
  const float* root1 = (const float*)d_in[2];
  const float* b1    = (const float*)d_in[3];
  const float* W2    = (const float*)d_in[4];
  const float* root2 = (const float*)d_in[5];
  const float* b2    = (const float*)d_in[6];
  const int* eidx    = (const int*)d_in[7];
  const int* etyp    = (const int*)d_in[8];
  const int* src = eidx;
  const int* dst = eidx + NE;
  float* out = (float*)d_out;

  // ws (u32): fcnt[1600] foff[1600] fcur[1600] cbnd[64] ccur[64] buf1[NE] buf2[NE]
  // h (bf16, 3.2 MB) overlays buf1 (dead after part2).
  unsigned* fcnt = (unsigned*)d_ws;
  unsigned* foff = fcnt + 1600;
  unsigned* fcur = foff + 1600;
  unsigned* cbnd = fcur + 1600;
  unsigned* ccur = cbnd + 64;
  unsigned* buf1 = ccur + 64;
  unsigned* buf2 = buf1 + NE;
  unsigned short* h = (unsigned short*)buf1;

  hipMemsetAsync(fcnt, 0, 1600 * 4, stream);
  hist_kernel<<<391, 256, 0, stream>>>(dst, fcnt);
  scan_kernel<<<1, 256, 0, stream>>>(fcnt, foff, fcur, cbnd, ccur);
  part1_kernel<<<782, 256, 0, stream>>>(src, dst, etyp, ccur, buf1);
  part2_kernel<<<782, 256, 0, stream>>>(buf1, cbnd, fcur, buf2);
  layer_kernel<0><<<NFINE, 256, 0, stream>>>(embed, h, W1, root1, b1, foff,
                                             buf2, h, out);
  layer_kernel<1><<<NFINE, 256, 0, stream>>>(embed, h, W2, root2, b2, foff,
                                             buf2, h, out);
}

// Round 5
// 312.007 us; speedup vs baseline: 2.4583x; 2.4583x over previous
//
#include <hip/hip_runtime.h>

// RGCN 2-layer, N=100000, E=3200000, R=8, H=C=16.
// Pipeline: fine histogram (dst>>6) -> scan -> 2-level radix partition by dst
// (coarse 49, fine 1563 buckets of 64 nodes) -> per-bucket layer blocks:
// block-local (node,rel) counting sort in LDS, then per-node REGISTER
// accumulation (8-deep gather ILP, no LDS atomics in the hot loop), scale by
// 1/cnt folded into the single LDS write, then 4 rel-block MFMAs + root MFMA
// + fused relu / log_softmax. h stored bf16 for layer-2 gathers.

constexpr int NN = 100000;
constexpr int NE = 3200000;
constexpr int NFINE = 1563;    // ceil(NN/64)
constexpr int NCOARSE = 49;    // ceil(NN/2048)
constexpr int CAP = 3072;      // LDS edge capacity/bucket (mean 2048, sigma 45)

typedef short bf16x8 __attribute__((ext_vector_type(8)));
typedef float f32x4 __attribute__((ext_vector_type(4)));

__device__ __forceinline__ short f2bf(float f) {
  union { float f; unsigned u; } v; v.f = f;
  unsigned r = v.u + 0x7FFFu + ((v.u >> 16) & 1u);  // RNE
  return (short)(r >> 16);
}
__device__ __forceinline__ float bf2f(unsigned short u) {
  union { unsigned u; float f; } v; v.u = ((unsigned)u) << 16; return v.f;
}

// K1: fine-bucket histogram (bucket = dst>>6), LDS-aggregated.
__global__ void __launch_bounds__(256) hist_kernel(
    const int* __restrict__ dst, unsigned* __restrict__ fcnt) {
  __shared__ unsigned h[NFINE];
  for (int i = threadIdx.x; i < NFINE; i += 256) h[i] = 0u;
  __syncthreads();
  const int base = blockIdx.x * 8192;
#pragma unroll
  for (int i = 0; i < 32; ++i) {
    int e = base + i * 256 + threadIdx.x;
    if (e < NE) atomicAdd(&h[(unsigned)dst[e] >> 6], 1u);
  }
  __syncthreads();
  for (int i = threadIdx.x; i < NFINE; i += 256)
    if (h[i]) atomicAdd(&fcnt[i], h[i]);
}

// K2: single-block exclusive scan of fcnt -> foff[0..NFINE], fine cursors,
// coarse boundaries and coarse cursors.
__global__ void __launch_bounds__(256) scan_kernel(
    const unsigned* __restrict__ fcnt, unsigned* __restrict__ foff,
    unsigned* __restrict__ fcur, unsigned* __restrict__ cbnd,
    unsigned* __restrict__ ccur) {
  __shared__ unsigned sh[256];
  unsigned v[7], s = 0;
#pragma unroll
  for (int j = 0; j < 7; ++j) {
    int idx = threadIdx.x * 7 + j;
    v[j] = (idx < NFINE) ? fcnt[idx] : 0u;
    s += v[j];
  }
  sh[threadIdx.x] = s;
  __syncthreads();
  for (int d = 1; d < 256; d <<= 1) {
    unsigned t = (threadIdx.x >= d) ? sh[threadIdx.x - d] : 0u;
    __syncthreads();
    sh[threadIdx.x] += t;
    __syncthreads();
  }
  unsigned run = sh[threadIdx.x] - s;
#pragma unroll
  for (int j = 0; j < 7; ++j) {
    int idx = threadIdx.x * 7 + j;
    if (idx <= NFINE) foff[idx] = run;
    if (idx < NFINE) fcur[idx] = run;
    run += v[j];
  }
  __syncthreads();
  if (threadIdx.x <= NCOARSE) {
    int f = threadIdx.x * 32; if (f > NFINE) f = NFINE;
    unsigned b = foff[f];
    cbnd[threadIdx.x] = b;
    if (threadIdx.x < NCOARSE) ccur[threadIdx.x] = b;
  }
}

// K3: coarse partition (dst>>11). Entry = src | rel<<17 | (dst&2047)<<20.
__global__ void __launch_bounds__(256) part1_kernel(
    const int* __restrict__ src, const int* __restrict__ dst,
    const int* __restrict__ typ, unsigned* __restrict__ ccur,
    unsigned* __restrict__ buf1) {
  __shared__ unsigned hist[NCOARSE];
  __shared__ unsigned gb[NCOARSE];
  if (threadIdx.x < NCOARSE) hist[threadIdx.x] = 0u;
  __syncthreads();
  const int base = blockIdx.x * 4096;
  unsigned ent[16], cb[16], rk[16];
#pragma unroll
  for (int i = 0; i < 16; ++i) {
    int e = base + i * 256 + threadIdx.x;
    if (e < NE) {
      unsigned d = (unsigned)dst[e];
      ent[i] = (unsigned)src[e] | ((unsigned)typ[e] << 17) | ((d & 2047u) << 20);
      cb[i] = d >> 11;
      rk[i] = atomicAdd(&hist[cb[i]], 1u);
    } else cb[i] = 0xFFFFFFFFu;
  }
  __syncthreads();
  if (threadIdx.x < NCOARSE && hist[threadIdx.x])
    gb[threadIdx.x] = atomicAdd(&ccur[threadIdx.x], hist[threadIdx.x]);
  __syncthreads();
#pragma unroll
  for (int i = 0; i < 16; ++i)
    if (cb[i] != 0xFFFFFFFFu) buf1[gb[cb[i]] + rk[i]] = ent[i];
}

// K4: fine partition within coarse segments. Final entry = low 26 bits.
__global__ void __launch_bounds__(256) part2_kernel(
    const unsigned* __restrict__ buf1, const unsigned* __restrict__ cbnd,
    unsigned* __restrict__ fcur, unsigned* __restrict__ buf2) {
  __shared__ unsigned hist[NFINE];
  __shared__ unsigned gb[NFINE];
  __shared__ unsigned cb_s[NCOARSE + 1];
  for (int i = threadIdx.x; i < NFINE; i += 256) hist[i] = 0u;
  if (threadIdx.x <= NCOARSE) cb_s[threadIdx.x] = cbnd[threadIdx.x];
  __syncthreads();
  const unsigned base = blockIdx.x * 4096u;
  int cc = 0;
  while (cc < NCOARSE - 1 && base >= cb_s[cc + 1]) ++cc;
  unsigned ent[16], fn[16], rk[16];
#pragma unroll
  for (int i = 0; i < 16; ++i) {
    unsigned p = base + i * 256u + threadIdx.x;
    if (p < (unsigned)NE) {
      unsigned e = buf1[p];
      while (p >= cb_s[cc + 1]) ++cc;
      fn[i] = (unsigned)cc * 32u + ((e >> 26) & 31u);
      ent[i] = e & 0x03FFFFFFu;
      rk[i] = atomicAdd(&hist[fn[i]], 1u);
    } else fn[i] = 0xFFFFFFFFu;
  }
  __syncthreads();
  for (int i = threadIdx.x; i < NFINE; i += 256)
    if (hist[i]) gb[i] = atomicAdd(&fcur[i], hist[i]);
  __syncthreads();
#pragma unroll
  for (int i = 0; i < 16; ++i)
    if (fn[i] != 0xFFFFFFFFu) buf2[gb[fn[i]] + rk[i]] = ent[i];
}

// K5/K6: per-bucket layer, 512 threads. Phases: stage segment to regs +
// (node,rel) LDS histogram -> 512-wide scan -> scatter to sorted LDS E ->
// per-node register accumulation (16-lane groups, 8-deep gathers) -> scaled
// write to S -> MFMA transform + epilogue.
template <int MODE>
__global__ void __launch_bounds__(512) layer_kernel(
    const float* __restrict__ Xf, const unsigned short* __restrict__ Xh,
    const float* __restrict__ W, const float* __restrict__ ROOT,
    const float* __restrict__ BIAS, const unsigned* __restrict__ foff,
    const unsigned* __restrict__ buf2, unsigned short* __restrict__ Hout,
    float* __restrict__ Fout) {
  __shared__ float S[64 * 132];      // scaled per-(node,rel) sums
  __shared__ unsigned E[CAP];        // sorted edge entries
  __shared__ unsigned cnt512[512];   // per-(node,rel) counts
  __shared__ unsigned cur512[512];   // scan workspace -> scatter cursors
  __shared__ unsigned nstart[65];    // per-node segment starts
  const int tid = threadIdx.x;

  for (int i = tid; i < 64 * 132; i += 512) S[i] = 0.f;
  cnt512[tid] = 0u;
  __syncthreads();

  const unsigned p0 = foff[blockIdx.x];
  const int seg = (int)(foff[blockIdx.x + 1] - p0);

  // Stage up to 6 entries/thread (3072 >= any bucket), histogram bins.
  unsigned e_0 = 0xFFFFFFFFu, e_1 = 0xFFFFFFFFu, e_2 = 0xFFFFFFFFu,
           e_3 = 0xFFFFFFFFu, e_4 = 0xFFFFFFFFu, e_5 = 0xFFFFFFFFu;
  if (tid < seg)          e_0 = buf2[p0 + tid];
  if (tid + 512 < seg)    e_1 = buf2[p0 + tid + 512];
  if (tid + 1024 < seg)   e_2 = buf2[p0 + tid + 1024];
  if (tid + 1536 < seg)   e_3 = buf2[p0 + tid + 1536];
  if (tid + 2048 < seg)   e_4 = buf2[p0 + tid + 2048];
  if (tid + 2560 < seg)   e_5 = buf2[p0 + tid + 2560];
  auto BIN = [](unsigned e) -> unsigned {
    return ((e >> 20) & 63u) * 8u + ((e >> 17) & 7u);
  };
  auto HB = [&](unsigned e) {
    if (e != 0xFFFFFFFFu) atomicAdd(&cnt512[BIN(e)], 1u);
  };
  HB(e_0); HB(e_1); HB(e_2); HB(e_3); HB(e_4); HB(e_5);
  __syncthreads();

  // Exclusive scan of cnt512 (Hillis-Steele over 512 threads).
  unsigned own = cnt512[tid];
  cur512[tid] = own;
  __syncthreads();
  for (int d = 1; d < 512; d <<= 1) {
    unsigned t = (tid >= d) ? cur512[tid - d] : 0u;
    __syncthreads();
    cur512[tid] += t;
    __syncthreads();
  }
  unsigned excl = cur512[tid] - own;
  __syncthreads();
  cur512[tid] = excl;
  if ((tid & 7) == 0) nstart[tid >> 3] = excl;
  if (tid == 0) nstart[64] = (unsigned)seg;
  __syncthreads();

  // Scatter into sorted E.
  auto SC = [&](unsigned e) {
    if (e != 0xFFFFFFFFu) {
      unsigned pos = atomicAdd(&cur512[BIN(e)], 1u);
      if (pos < (unsigned)CAP) E[pos] = e;
    }
  };
  SC(e_0); SC(e_1); SC(e_2); SC(e_3); SC(e_4); SC(e_5);
  __syncthreads();

  // Register accumulation: 32 groups of 16 lanes; group gi owns nodes
  // gi*2, gi*2+1. Lane = feature component c16.
  const int gi = tid >> 4;
  const int c16 = tid & 15;

  auto LDX = [&](unsigned e) -> float {
    unsigned sr = e & 0x1FFFFu;
    if (MODE) return bf2f(Xh[(size_t)sr * 16 + c16]);
    return Xf[(size_t)sr * 16 + c16];
  };

#pragma unroll
  for (int k = 0; k < 2; ++k) {
    const int nd = gi * 2 + k;
    int p = (int)nstart[nd], pe = (int)nstart[nd + 1];
    float s0 = 0.f, s1 = 0.f, s2 = 0.f, s3 = 0.f,
          s4 = 0.f, s5 = 0.f, s6 = 0.f, s7 = 0.f;
    auto ACCU = [&](unsigned e, float xv) {
      unsigned rr = (e >> 17) & 7u;
      s0 += (rr == 0u) ? xv : 0.f; s1 += (rr == 1u) ? xv : 0.f;
      s2 += (rr == 2u) ? xv : 0.f; s3 += (rr == 3u) ? xv : 0.f;
      s4 += (rr == 4u) ? xv : 0.f; s5 += (rr == 5u) ? xv : 0.f;
      s6 += (rr == 6u) ? xv : 0.f; s7 += (rr == 7u) ? xv : 0.f;
    };
    for (; p + 8 <= pe; p += 8) {
      unsigned f0 = E[p],     f1 = E[p + 1], f2 = E[p + 2], f3 = E[p + 3];
      unsigned f4 = E[p + 4], f5 = E[p + 5], f6 = E[p + 6], f7 = E[p + 7];
      float x0 = LDX(f0), x1 = LDX(f1), x2 = LDX(f2), x3 = LDX(f3);
      float x4 = LDX(f4), x5 = LDX(f5), x6 = LDX(f6), x7 = LDX(f7);
      ACCU(f0, x0); ACCU(f1, x1); ACCU(f2, x2); ACCU(f3, x3);
      ACCU(f4, x4); ACCU(f5, x5); ACCU(f6, x6); ACCU(f7, x7);
    }
    for (; p < pe; ++p) {
      unsigned f = E[p];
      ACCU(f, LDX(f));
    }
    // Scale by 1/max(cnt,1) and write (single writer per address).
    float* sp = S + nd * 132 + c16;
    const unsigned* cp = cnt512 + nd * 8;
#define WR(R, SV)                                                         \
    {                                                                     \
      unsigned ct = cp[R];                                                \
      float iv = 1.f / (float)(ct ? ct : 1u);                             \
      sp[(R) * 16] = (SV) * iv;                                           \
    }
    WR(0, s0) WR(1, s1) WR(2, s2) WR(3, s3)
    WR(4, s4) WR(5, s5) WR(6, s6) WR(7, s7)
#undef WR
  }
  __syncthreads();

  // MFMA phase: waves 0..3 each own a 16-node tile.
  const int w = tid >> 6;
  if (w >= 4) return;
  const int lane = tid & 63;
  const int fc = lane & 15;
  const int g = lane >> 4;
  const int n0 = blockIdx.x * 64 + w * 16;

  bf16x8 b0, b1, b2, b3, brt;
#pragma unroll
  for (int j = 0; j < 8; ++j) {
    int kq = g * 8 + j; int rb = kq >> 4; int kk = kq & 15;
    b0[j] = f2bf(W[(rb + 0) * 256 + kk * 16 + fc]);
    b1[j] = f2bf(W[(rb + 2) * 256 + kk * 16 + fc]);
    b2[j] = f2bf(W[(rb + 4) * 256 + kk * 16 + fc]);
    b3[j] = f2bf(W[(rb + 6) * 256 + kk * 16 + fc]);
    brt[j] = (kq < 16) ? f2bf(ROOT[kq * 16 + fc]) : (short)0;
  }

  const int kk0 = (g & 1) * 8;
  const int rsel = g >> 1;
  const int dl16 = w * 16 + fc;
  bf16x8 a0, a1, a2, a3;
#define LDA(AM, M)                                                        \
  {                                                                       \
    const float* sp2 = S + dl16 * 132 + (2 * (M) + rsel) * 16 + kk0;      \
    float4 u = *reinterpret_cast<const float4*>(sp2);                     \
    float4 v2 = *reinterpret_cast<const float4*>(sp2 + 4);                \
    AM[0] = f2bf(u.x); AM[1] = f2bf(u.y); AM[2] = f2bf(u.z);              \
    AM[3] = f2bf(u.w); AM[4] = f2bf(v2.x); AM[5] = f2bf(v2.y);            \
    AM[6] = f2bf(v2.z); AM[7] = f2bf(v2.w);                               \
  }
  LDA(a0, 0) LDA(a1, 1) LDA(a2, 2) LDA(a3, 3)
#undef LDA

  bf16x8 ar = {0, 0, 0, 0, 0, 0, 0, 0};
  if (g < 2) {
    int node = n0 + fc;
    if (node < NN) {
      if (MODE == 0) {
        const float* xp = Xf + (size_t)node * 16 + g * 8;
        float4 pp = *reinterpret_cast<const float4*>(xp);
        float4 qq = *reinterpret_cast<const float4*>(xp + 4);
        ar[0] = f2bf(pp.x); ar[1] = f2bf(pp.y); ar[2] = f2bf(pp.z);
        ar[3] = f2bf(pp.w); ar[4] = f2bf(qq.x); ar[5] = f2bf(qq.y);
        ar[6] = f2bf(qq.z); ar[7] = f2bf(qq.w);
      } else {
        ar = *reinterpret_cast<const bf16x8*>(Xh + (size_t)node * 16 + g * 8);
      }
    }
  }

  const float bc = BIAS[fc];
  f32x4 acc = {bc, bc, bc, bc};
  acc = __builtin_amdgcn_mfma_f32_16x16x32_bf16(a0, b0, acc, 0, 0, 0);
  acc = __builtin_amdgcn_mfma_f32_16x16x32_bf16(a1, b1, acc, 0, 0, 0);
  acc = __builtin_amdgcn_mfma_f32_16x16x32_bf16(a2, b2, acc, 0, 0, 0);
  acc = __builtin_amdgcn_mfma_f32_16x16x32_bf16(a3, b3, acc, 0, 0, 0);
  acc = __builtin_amdgcn_mfma_f32_16x16x32_bf16(ar, brt, acc, 0, 0, 0);

  if (MODE == 0) {
#pragma unroll
    for (int r2 = 0; r2 < 4; ++r2) {
      int node = n0 + g * 4 + r2;
      if (node < NN)
        Hout[(size_t)node * 16 + fc] = (unsigned short)f2bf(fmaxf(acc[r2], 0.f));
    }
  } else {
#pragma unroll
    for (int r2 = 0; r2 < 4; ++r2) {
      int node = n0 + g * 4 + r2;
      float zv = acc[r2];
      float mx = zv;
      mx = fmaxf(mx, __shfl_xor(mx, 1));
      mx = fmaxf(mx, __shfl_xor(mx, 2));
      mx = fmaxf(mx, __shfl_xor(mx, 4));
      mx = fmaxf(mx, __shfl_xor(mx, 8));
      float sm = expf(zv - mx);
      sm += __shfl_xor(sm, 1);
      sm += __shfl_xor(sm, 2);
      sm += __shfl_xor(sm, 4);
      sm += __shfl_xor(sm, 8);
      if (node < NN)
        Fout[(size_t)node * 16 + fc] = zv - mx - logf(sm);
    }
  }
}

extern "C" void kernel_launch(void* const* d_in, const int* in_sizes, int n_in,
                              void* d_out, int out_size, void* d_ws, size_t ws_size,
                              hipStream_t stream) {
  const float* embed = (const float*)d_in[0];
  const float* W1    = (const float*)d_in[1];
  const float* root1 = (const float*)d_in[2];
  const float* b1    = (const float*)d_in[3];
  const float* W2    = (const float*)d_in[4];
  const float* root2 = (const float*)d_in[5];
  const float* b2    = (const float*)d_in[6];
  const int* eidx    = (const int*)d_in[7];
  const int* etyp    = (const int*)d_in[8];
  const int* src = eidx;
  const int* dst = eidx + NE;
  float* out = (float*)d_out;

  // ws (u32): fcnt[1600] foff[1600] fcur[1600] cbnd[64] ccur[64] buf1[NE] buf2[NE]
  // h (bf16, 3.2 MB) overlays buf1 (dead after part2).
  unsigned* fcnt = (unsigned*)d_ws;
  unsigned* foff = fcnt + 1600;
  unsigned* fcur = foff + 1600;
  unsigned* cbnd = fcur + 1600;
  unsigned* ccur = cbnd + 64;
  unsigned* buf1 = ccur + 64;
  unsigned* buf2 = buf1 + NE;
  unsigned short* h = (unsigned short*)buf1;

  hipMemsetAsync(fcnt, 0, 1600 * 4, stream);
  hist_kernel<<<391, 256, 0, stream>>>(dst, fcnt);
  scan_kernel<<<1, 256, 0, stream>>>(fcnt, foff, fcur, cbnd, ccur);
  part1_kernel<<<782, 256, 0, stream>>>(src, dst, etyp, ccur, buf1);
  part2_kernel<<<782, 256, 0, stream>>>(buf1, cbnd, fcur, buf2);
  layer_kernel<0><<<NFINE, 512, 0, stream>>>(embed, h, W1, root1, b1, foff,
                                             buf2, h, out);
  layer_kernel<1><<<NFINE, 512, 0, stream>>>(embed, h, W2, root2, b2, foff,
                                             buf2, h, out);
}